// Round 5
// baseline (1647.359 us; speedup 1.0000x reference)
//
#include <hip/hip_runtime.h>
#include <hip/hip_bf16.h>

// GCN 2-layer, bucket-direct aggregation (no CSR, no global fp32 atomics):
//   dis = rsqrt(indeg_by_dst + 1)
//   hs  = bf16( (x@W) * dis[row] )       (GEMM epilogue, fp32 math)
//   out[i] = act( dis[i] * (sum_{s in N(i)} hs[s] + hs[i]) + b )
// Edges are multisplit into per-bucket slabs (bucket = 256 dst nodes) with
// LDS-staged coalesced dumps; aggregation runs one block per bucket with a
// 64KB LDS fp32 accumulator fed by ds_add_f32 (conflict-free, lane=feature).

#define FOUT 64
#define BW 256        // nodes per bucket
#define BSH 8
#define MAXB 512      // >= ceil(n/BW)
#define CHUNK 16384   // edges per scatter block
#define SLAB 6144     // slab capacity (mean 4092 for E=1.6M,B=391; +32 sigma)

__device__ __forceinline__ float bf2f(unsigned short u) {
    union { unsigned int i; float f; } c;
    c.i = ((unsigned int)u) << 16;
    return c.f;
}
__device__ __forceinline__ unsigned short f2bf(float f) {
    union { float f; unsigned int i; } c;
    c.f = f;
    unsigned int i = c.i;
    return (unsigned short)((i + 0x7FFFu + ((i >> 16) & 1u)) >> 16);  // RN-even
}

// ---- init per-bucket cursors to slab bases -------------------------------
__global__ void init_gcur(int* __restrict__ gcur, int B) {
    int b = blockIdx.x * 256 + threadIdx.x;
    if (b < B) gcur[b] = b * SLAB;
}

// ---- multisplit scatter with LDS-staged coalesced dump -------------------
__global__ __launch_bounds__(512) void bucket_scatter(
    const int* __restrict__ src, const int* __restrict__ dst,
    int* __restrict__ gcur, int* __restrict__ ebuf, int E, int B) {
    __shared__ int lwords[CHUNK];   // 64 KB staging
    __shared__ int hcnt[MAXB];
    __shared__ int lbase[MAXB];
    __shared__ int gbase[MAXB];
    __shared__ int lcur[MAXB];
    const int chunk0 = blockIdx.x * CHUNK;
    const int t = threadIdx.x;

    hcnt[t] = 0;
    if (t + 512 < MAXB) hcnt[t + 512] = 0;
    __syncthreads();
    // pass 1: histogram
#pragma unroll 4
    for (int k = 0; k < CHUNK / 512; k++) {
        int e = chunk0 + k * 512 + t;
        if (e < E) atomicAdd(&hcnt[dst[e] >> BSH], 1);
    }
    __syncthreads();
    // exclusive scan of hcnt (Hillis-Steele over MAXB with 512 threads)
    {
        int v0 = hcnt[t], v1 = hcnt[t + 512 < MAXB ? t + 512 : t];
        // MAXB==512 so only v0 path used; keep simple:
        int v = v0;
        lbase[t] = v;
        __syncthreads();
        for (int off = 1; off < 512; off <<= 1) {
            int x = (t >= off) ? lbase[t - off] : 0;
            __syncthreads();
            lbase[t] += x;
            __syncthreads();
        }
        int ex = lbase[t] - v;  // exclusive
        __syncthreads();
        lbase[t] = ex;
        lcur[t] = ex;
        (void)v1;
    }
    __syncthreads();
    // reservations: one global atomic per (block,bucket)
    if (t < B) {
        int c = hcnt[t];
        gbase[t] = c ? atomicAdd(&gcur[t], c) : 0;
    }
    __syncthreads();
    // pass 2: rank into LDS staging
#pragma unroll 4
    for (int k = 0; k < CHUNK / 512; k++) {
        int e = chunk0 + k * 512 + t;
        if (e < E) {
            int d = dst[e];
            int b = d >> BSH;
            int r = atomicAdd(&lcur[b], 1);
            lwords[r] = src[e] | ((d & (BW - 1)) << 17);  // src < 2^17
        }
    }
    __syncthreads();
    // dump: per-bucket contiguous runs, coalesced
    const int wid = t >> 6, lane = t & 63;
    for (int b = wid; b < B; b += 8) {
        int c = hcnt[b];
        int lb = lbase[b];
        int gb = gbase[b];
        for (int i = lane; i < c; i += 64) ebuf[gb + i] = lwords[lb + i];
    }
}

// ---- per-bucket degree -> dis --------------------------------------------
__global__ __launch_bounds__(256) void bucket_dis(
    const int* __restrict__ ebuf, const int* __restrict__ gcur,
    float* __restrict__ dis, int n) {
    __shared__ int ldeg[BW];
    const int b = blockIdx.x, t = threadIdx.x;
    const int node0 = b << BSH;
    const int ebeg = b * SLAB;
    const int cnt = gcur[b] - ebeg;
    ldeg[t] = 0;
    __syncthreads();
    for (int i = t; i < cnt; i += 256) atomicAdd(&ldeg[(ebuf[ebeg + i] >> 17) & 255], 1);
    __syncthreads();
    if (node0 + t < n) dis[node0 + t] = rsqrtf((float)ldeg[t] + 1.0f);
}

// ---- GEMM: HS[n x 64] = bf16( (X[n x K] @ W[K x 64]) * dis[row] ) --------
template <int K>
__global__ __launch_bounds__(256) void gemm_xw(const float* __restrict__ X,
                                               const float* __restrict__ W,
                                               const float* __restrict__ dis,
                                               unsigned short* __restrict__ HS, int n) {
    constexpr int KP = K + 4;
    __shared__ float xs[64 * KP];
    __shared__ float ws[K * 64];
    const int tid  = threadIdx.x;
    const int row0 = blockIdx.x * 64;

    for (int idx = tid; idx < 64 * K / 4; idx += 256) {
        int r = (idx * 4) / K;
        int c = (idx * 4) % K;
        float4 v = make_float4(0.f, 0.f, 0.f, 0.f);
        if (row0 + r < n) v = *(const float4*)&X[(size_t)(row0 + r) * K + c];
        *(float4*)&xs[r * KP + c] = v;
    }
    for (int idx = tid; idx < K * 64 / 4; idx += 256) {
        *(float4*)&ws[idx * 4] = *(const float4*)&W[idx * 4];
    }
    __syncthreads();

    const int tr = tid >> 4;
    const int tc = tid & 15;
    float acc[4][4];
#pragma unroll
    for (int i = 0; i < 4; i++)
#pragma unroll
        for (int j = 0; j < 4; j++) acc[i][j] = 0.f;

    for (int k = 0; k < K; k += 4) {
        float4 xv[4], wv[4];
#pragma unroll
        for (int i = 0; i < 4; i++) xv[i] = *(float4*)&xs[(tr * 4 + i) * KP + k];
#pragma unroll
        for (int kk = 0; kk < 4; kk++) wv[kk] = *(float4*)&ws[(k + kk) * 64 + tc * 4];
#pragma unroll
        for (int i = 0; i < 4; i++) {
            float xi[4] = {xv[i].x, xv[i].y, xv[i].z, xv[i].w};
#pragma unroll
            for (int kk = 0; kk < 4; kk++) {
                acc[i][0] = fmaf(xi[kk], wv[kk].x, acc[i][0]);
                acc[i][1] = fmaf(xi[kk], wv[kk].y, acc[i][1]);
                acc[i][2] = fmaf(xi[kk], wv[kk].z, acc[i][2]);
                acc[i][3] = fmaf(xi[kk], wv[kk].w, acc[i][3]);
            }
        }
    }
#pragma unroll
    for (int i = 0; i < 4; i++) {
        int r = row0 + tr * 4 + i;
        if (r < n) {
            float dr = dis[r];
            ushort4 o;
            o.x = f2bf(acc[i][0] * dr);
            o.y = f2bf(acc[i][1] * dr);
            o.z = f2bf(acc[i][2] * dr);
            o.w = f2bf(acc[i][3] * dr);
            *(ushort4*)&HS[(size_t)r * FOUT + tc * 4] = o;
        }
    }
}

// ---- bucket aggregate: one block per bucket, LDS fp32 accumulator --------
template <bool RELU>
__global__ __launch_bounds__(512) void bucket_agg(
    const unsigned short* __restrict__ hs, const int* __restrict__ ebuf,
    const int* __restrict__ gcur, const float* __restrict__ dis,
    const float* __restrict__ bias, float* __restrict__ out, int n) {
    __shared__ float acc[BW * FOUT];  // 64 KB
    const int b = blockIdx.x, t = threadIdx.x;
    const int node0 = b << BSH;
    const int ebeg = b * SLAB;
    const int cnt = gcur[b] - ebeg;

    for (int i = t; i < BW * FOUT; i += 512) acc[i] = 0.0f;
    __syncthreads();

    const int wid = t >> 6, j = t & 63;
    for (int chunk = wid * 64; chunk < cnt; chunk += 8 * 64) {
        int m = cnt - chunk;
        if (m > 64) m = 64;
        int ew = (j < m) ? ebuf[ebeg + chunk + j] : 0;
        int q = 0;
        for (; q + 8 <= m; q += 8) {
            int w0 = __shfl(ew, q + 0), w1 = __shfl(ew, q + 1);
            int w2 = __shfl(ew, q + 2), w3 = __shfl(ew, q + 3);
            int w4 = __shfl(ew, q + 4), w5 = __shfl(ew, q + 5);
            int w6 = __shfl(ew, q + 6), w7 = __shfl(ew, q + 7);
            float v0 = bf2f(hs[(size_t)(w0 & 0x1FFFF) * FOUT + j]);
            float v1 = bf2f(hs[(size_t)(w1 & 0x1FFFF) * FOUT + j]);
            float v2 = bf2f(hs[(size_t)(w2 & 0x1FFFF) * FOUT + j]);
            float v3 = bf2f(hs[(size_t)(w3 & 0x1FFFF) * FOUT + j]);
            float v4 = bf2f(hs[(size_t)(w4 & 0x1FFFF) * FOUT + j]);
            float v5 = bf2f(hs[(size_t)(w5 & 0x1FFFF) * FOUT + j]);
            float v6 = bf2f(hs[(size_t)(w6 & 0x1FFFF) * FOUT + j]);
            float v7 = bf2f(hs[(size_t)(w7 & 0x1FFFF) * FOUT + j]);
            atomicAdd(&acc[((w0 >> 17) & 255) * FOUT + j], v0);
            atomicAdd(&acc[((w1 >> 17) & 255) * FOUT + j], v1);
            atomicAdd(&acc[((w2 >> 17) & 255) * FOUT + j], v2);
            atomicAdd(&acc[((w3 >> 17) & 255) * FOUT + j], v3);
            atomicAdd(&acc[((w4 >> 17) & 255) * FOUT + j], v4);
            atomicAdd(&acc[((w5 >> 17) & 255) * FOUT + j], v5);
            atomicAdd(&acc[((w6 >> 17) & 255) * FOUT + j], v6);
            atomicAdd(&acc[((w7 >> 17) & 255) * FOUT + j], v7);
        }
        for (; q < m; q++) {
            int w = __shfl(ew, q);
            float v = bf2f(hs[(size_t)(w & 0x1FFFF) * FOUT + j]);
            atomicAdd(&acc[((w >> 17) & 255) * FOUT + j], v);
        }
    }
    __syncthreads();

    const int nn = min(BW, n - node0);
    for (int idx = t; idx < nn * FOUT; idx += 512) {
        int row = idx >> 6, jj = idx & 63;
        int node = node0 + row;
        float self = bf2f(hs[(size_t)node * FOUT + jj]);
        float v = dis[node] * (acc[idx] + self) + bias[jj];
        if (RELU) v = fmaxf(v, 0.0f);
        out[(size_t)node * FOUT + jj] = v;
    }
}

extern "C" void kernel_launch(void* const* d_in, const int* in_sizes, int n_in,
                              void* d_out, int out_size, void* d_ws, size_t ws_size,
                              hipStream_t stream) {
    const float* x  = (const float*)d_in[0];
    const int*   ei = (const int*)d_in[1];
    const float* W1 = (const float*)d_in[2];
    const float* b1 = (const float*)d_in[3];
    const float* W2 = (const float*)d_in[4];
    const float* b2 = (const float*)d_in[5];

    const int n = in_sizes[0] / 128;
    const int E = in_sizes[1] / 2;
    const int* srcp = ei;
    const int* dstp = ei + E;

    float* out = (float*)d_out;

    const int B = (n + BW - 1) / BW;

    // workspace layout
    int*            gcur = (int*)d_ws;               // MAXB
    int*            ebuf = gcur + MAXB;              // B*SLAB
    float*          dis  = (float*)(ebuf + (size_t)B * SLAB);  // n floats
    unsigned short* hs   = (unsigned short*)(dis + n);         // n*64 bf16

    // edge bucketing (shared by both layers) + degree/dis
    init_gcur<<<(B + 255) / 256, 256, 0, stream>>>(gcur, B);
    bucket_scatter<<<(E + CHUNK - 1) / CHUNK, 512, 0, stream>>>(srcp, dstp, gcur, ebuf, E, B);
    bucket_dis<<<B, 256, 0, stream>>>(ebuf, gcur, dis, n);

    // layer 1
    gemm_xw<128><<<(n + 63) / 64, 256, 0, stream>>>(x, W1, dis, hs, n);
    bucket_agg<true><<<B, 512, 0, stream>>>(hs, ebuf, gcur, dis, b1, out, n);

    // layer 2
    gemm_xw<64><<<(n + 63) / 64, 256, 0, stream>>>(out, W2, dis, hs, n);
    bucket_agg<false><<<B, 512, 0, stream>>>(hs, ebuf, gcur, dis, b2, out, n);
}

// Round 6
// 337.759 us; speedup vs baseline: 4.8773x; 4.8773x over previous
//
#include <hip/hip_runtime.h>
#include <hip/hip_bf16.h>

// GCN 2-layer via CSR gather:
//   dis = rsqrt(indeg_by_dst + 1)
//   hs  = bf16( (x@W) * dis[row] )     (GEMM epilogue, fp32 math)
//   out[i] = act( dis[i] * (hs[i] + sum_{s in N(i)} hs[s]) + b )
// CSR built via fixed-slab multisplit (bucket = 256 dst nodes); per-bucket
// degree/scan/rowptr/dis/col all in LDS. Aggregate = wave-per-node gather
// (massive TLP; R5 showed block-per-bucket starves the latency hiding).

#define FOUT 64
#define BW 256        // nodes per bucket
#define BSH 8
#define MAXB 512      // >= ceil(n/BW)
#define CHUNK 16384   // edges per scatter block
#define SLAB 6144     // slab capacity (mean 4092 for E=1.6M,B=391)
#define MAXSEG 8192   // LDS col staging in csr_build (>= SLAB)

__device__ __forceinline__ float bf2f(unsigned short u) {
    union { unsigned int i; float f; } c;
    c.i = ((unsigned int)u) << 16;
    return c.f;
}
__device__ __forceinline__ unsigned short f2bf(float f) {
    union { float f; unsigned int i; } c;
    c.f = f;
    unsigned int i = c.i;
    return (unsigned short)((i + 0x7FFFu + ((i >> 16) & 1u)) >> 16);  // RN-even
}

// ---- init per-bucket cursors to slab bases -------------------------------
__global__ void init_gcur(int* __restrict__ gcur, int B) {
    int b = blockIdx.x * 256 + threadIdx.x;
    if (b < B) gcur[b] = b * SLAB;
}

// ---- multisplit scatter: per-(block,bucket) contiguous runs --------------
__global__ __launch_bounds__(512) void bucket_scatter(
    const int* __restrict__ src, const int* __restrict__ dst,
    int* __restrict__ gcur, int* __restrict__ ebuf, int E, int B) {
    __shared__ int h[MAXB];
    __shared__ int basea[MAXB];
    const int chunk0 = blockIdx.x * CHUNK;
    const int t = threadIdx.x;
    h[t] = 0;
    __syncthreads();
#pragma unroll 4
    for (int k = 0; k < CHUNK / 512; k++) {
        int e = chunk0 + k * 512 + t;
        if (e < E) atomicAdd(&h[dst[e] >> BSH], 1);
    }
    __syncthreads();
    if (t < B) {
        int c = h[t];
        basea[t] = c ? atomicAdd(&gcur[t], c) : 0;
        h[t] = 0;
    }
    __syncthreads();
#pragma unroll 4
    for (int k = 0; k < CHUNK / 512; k++) {
        int e = chunk0 + k * 512 + t;
        if (e < E) {
            int d = dst[e];
            int b = d >> BSH;
            int r = atomicAdd(&h[b], 1);
            ebuf[basea[b] + r] = src[e] | ((d & (BW - 1)) << 17);  // src < 2^17
        }
    }
}

// ---- scan bucket counts -> bbase (single block) --------------------------
__global__ __launch_bounds__(512) void bucket_scan(const int* __restrict__ gcur,
                                                   int B, int* __restrict__ bbase,
                                                   int* __restrict__ rowptr,
                                                   int n, int E) {
    __shared__ int ts[MAXB];
    int t = threadIdx.x;
    int v = (t < B) ? (gcur[t] - t * SLAB) : 0;
    ts[t] = v;
    __syncthreads();
    for (int off = 1; off < MAXB; off <<= 1) {
        int x = (t >= off) ? ts[t - off] : 0;
        __syncthreads();
        ts[t] += x;
        __syncthreads();
    }
    if (t < B) bbase[t] = ts[t] - v;  // exclusive prefix
    if (t == 0) {
        bbase[B] = E;
        rowptr[n] = E;
    }
}

// ---- per-bucket CSR finalize: degree, scan, rowptr, dis, col — all LDS ---
__global__ __launch_bounds__(512) void csr_build(
    const int* __restrict__ ebuf, const int* __restrict__ gcur,
    const int* __restrict__ bbase, int* __restrict__ rowptr,
    float* __restrict__ dis, int* __restrict__ col, int n) {
    __shared__ int ldeg[BW];
    __shared__ int lscan[BW];
    __shared__ int colbuf[MAXSEG];
    const int b = blockIdx.x, t = threadIdx.x;
    const int node0 = b << BSH;
    const int nn = min(BW, n - node0);
    const int ebeg = b * SLAB;
    const int cnt = gcur[b] - ebeg;
    const int segbeg = bbase[b];

    if (t < BW) ldeg[t] = 0;
    __syncthreads();
    for (int i = t; i < cnt; i += 512) atomicAdd(&ldeg[ebuf[ebeg + i] >> 17], 1);
    __syncthreads();
    int v = 0;
    if (t < BW) {
        v = ldeg[t];
        lscan[t] = v;
    }
    __syncthreads();
    for (int off = 1; off < BW; off <<= 1) {
        int x = 0;
        if (t < BW && t >= off) x = lscan[t - off];
        __syncthreads();
        if (t < BW) lscan[t] += x;
        __syncthreads();
    }
    if (t < nn) {
        int ex = lscan[t] - v;  // exclusive prefix within bucket
        rowptr[node0 + t] = segbeg + ex;
        dis[node0 + t] = rsqrtf((float)v + 1.0f);  // +1 self-loop
    }
    __syncthreads();
    if (t < BW) ldeg[t] = lscan[t] - v;  // reuse as write cursor
    __syncthreads();
    for (int i = t; i < cnt; i += 512) {
        int w = ebuf[ebeg + i];
        int r = atomicAdd(&ldeg[w >> 17], 1);
        colbuf[r] = w & 0x1FFFF;
    }
    __syncthreads();
    for (int i = t; i < cnt; i += 512) col[segbeg + i] = colbuf[i];
}

// ---- GEMM: HS[n x 64] = bf16( (X[n x K] @ W[K x 64]) * dis[row] ) --------
template <int K>
__global__ __launch_bounds__(256) void gemm_xw(const float* __restrict__ X,
                                               const float* __restrict__ W,
                                               const float* __restrict__ dis,
                                               unsigned short* __restrict__ HS, int n) {
    constexpr int KP = K + 4;
    __shared__ float xs[64 * KP];
    __shared__ float ws[K * 64];
    const int tid  = threadIdx.x;
    const int row0 = blockIdx.x * 64;

    for (int idx = tid; idx < 64 * K / 4; idx += 256) {
        int r = (idx * 4) / K;
        int c = (idx * 4) % K;
        float4 v = make_float4(0.f, 0.f, 0.f, 0.f);
        if (row0 + r < n) v = *(const float4*)&X[(size_t)(row0 + r) * K + c];
        *(float4*)&xs[r * KP + c] = v;
    }
    for (int idx = tid; idx < K * 64 / 4; idx += 256) {
        *(float4*)&ws[idx * 4] = *(const float4*)&W[idx * 4];
    }
    __syncthreads();

    const int tr = tid >> 4;
    const int tc = tid & 15;
    float acc[4][4];
#pragma unroll
    for (int i = 0; i < 4; i++)
#pragma unroll
        for (int j = 0; j < 4; j++) acc[i][j] = 0.f;

    for (int k = 0; k < K; k += 4) {
        float4 xv[4], wv[4];
#pragma unroll
        for (int i = 0; i < 4; i++) xv[i] = *(float4*)&xs[(tr * 4 + i) * KP + k];
#pragma unroll
        for (int kk = 0; kk < 4; kk++) wv[kk] = *(float4*)&ws[(k + kk) * 64 + tc * 4];
#pragma unroll
        for (int i = 0; i < 4; i++) {
            float xi[4] = {xv[i].x, xv[i].y, xv[i].z, xv[i].w};
#pragma unroll
            for (int kk = 0; kk < 4; kk++) {
                acc[i][0] = fmaf(xi[kk], wv[kk].x, acc[i][0]);
                acc[i][1] = fmaf(xi[kk], wv[kk].y, acc[i][1]);
                acc[i][2] = fmaf(xi[kk], wv[kk].z, acc[i][2]);
                acc[i][3] = fmaf(xi[kk], wv[kk].w, acc[i][3]);
            }
        }
    }
#pragma unroll
    for (int i = 0; i < 4; i++) {
        int r = row0 + tr * 4 + i;
        if (r < n) {
            float dr = dis[r];
            ushort4 o;
            o.x = f2bf(acc[i][0] * dr);
            o.y = f2bf(acc[i][1] * dr);
            o.z = f2bf(acc[i][2] * dr);
            o.w = f2bf(acc[i][3] * dr);
            *(ushort4*)&HS[(size_t)r * FOUT + tc * 4] = o;
        }
    }
}

// ---- aggregate: one wave per node, lane = feature, bf16 gathers ----------
template <bool RELU>
__global__ __launch_bounds__(256) void aggregate(
    const unsigned short* __restrict__ hs, const int* __restrict__ rowptr,
    const int* __restrict__ col, const float* __restrict__ dis,
    const float* __restrict__ bias, float* __restrict__ out, int n) {
    int i = blockIdx.x * 4 + (threadIdx.x >> 6);
    if (i >= n) return;
    int j = threadIdx.x & 63;
    int beg = rowptr[i], end = rowptr[i + 1];
    float acc = bf2f(hs[(size_t)i * FOUT + j]);  // self-loop term

    for (int chunk = beg; chunk < end; chunk += 64) {
        int m = end - chunk;
        if (m > 64) m = 64;
        int c = (j < m) ? col[chunk + j] : 0;
        int q = 0;
        for (; q + 4 <= m; q += 4) {
            int s0 = __shfl(c, q);
            int s1 = __shfl(c, q + 1);
            int s2 = __shfl(c, q + 2);
            int s3 = __shfl(c, q + 3);
            float v0 = bf2f(hs[(size_t)s0 * FOUT + j]);
            float v1 = bf2f(hs[(size_t)s1 * FOUT + j]);
            float v2 = bf2f(hs[(size_t)s2 * FOUT + j]);
            float v3 = bf2f(hs[(size_t)s3 * FOUT + j]);
            acc += v0 + v1 + v2 + v3;
        }
        for (; q < m; q++) {
            int s = __shfl(c, q);
            acc += bf2f(hs[(size_t)s * FOUT + j]);
        }
    }
    float v = dis[i] * acc + bias[j];
    if (RELU) v = fmaxf(v, 0.0f);
    out[(size_t)i * FOUT + j] = v;
}

extern "C" void kernel_launch(void* const* d_in, const int* in_sizes, int n_in,
                              void* d_out, int out_size, void* d_ws, size_t ws_size,
                              hipStream_t stream) {
    const float* x  = (const float*)d_in[0];
    const int*   ei = (const int*)d_in[1];
    const float* W1 = (const float*)d_in[2];
    const float* b1 = (const float*)d_in[3];
    const float* W2 = (const float*)d_in[4];
    const float* b2 = (const float*)d_in[5];

    const int n = in_sizes[0] / 128;
    const int E = in_sizes[1] / 2;
    const int* srcp = ei;
    const int* dstp = ei + E;

    float* out = (float*)d_out;

    const int B = (n + BW - 1) / BW;

    // workspace layout
    int*            gcur   = (int*)d_ws;           // MAXB
    int*            bbase  = gcur + MAXB;          // MAXB+4
    int*            rowptr = bbase + MAXB + 4;     // n+4
    int*            col    = rowptr + n + 4;       // E
    float*          dis    = (float*)(col + E);    // n floats
    unsigned short* hs     = (unsigned short*)(dis + n);  // n*64 bf16
    int*            ebuf   = (int*)hs;             // B*SLAB ints — aliases hs
                                                   // (ebuf dead before gemm1 writes hs)

    // CSR build: slab multisplit -> per-bucket LDS finalize
    init_gcur<<<(B + 255) / 256, 256, 0, stream>>>(gcur, B);
    bucket_scatter<<<(E + CHUNK - 1) / CHUNK, 512, 0, stream>>>(srcp, dstp, gcur, ebuf, E, B);
    bucket_scan<<<1, MAXB, 0, stream>>>(gcur, B, bbase, rowptr, n, E);
    csr_build<<<B, 512, 0, stream>>>(ebuf, gcur, bbase, rowptr, dis, col, n);

    // layer 1: hs = bf16((x@W1)*dis) ; out = relu(dis*(hs_self + sum hs[nbr]) + b1)
    gemm_xw<128><<<(n + 63) / 64, 256, 0, stream>>>(x, W1, dis, hs, n);
    aggregate<true><<<(n + 3) / 4, 256, 0, stream>>>(hs, rowptr, col, dis, b1, out, n);

    // layer 2: hs = bf16((out@W2)*dis) ; out = dis*(hs_self + sum hs[nbr]) + b2
    gemm_xw<64><<<(n + 63) / 64, 256, 0, stream>>>(out, W2, dis, hs, n);
    aggregate<false><<<(n + 3) / 4, 256, 0, stream>>>(hs, rowptr, col, dis, b2, out, n);
}

// Round 7
// 324.484 us; speedup vs baseline: 5.0769x; 1.0409x over previous
//
#include <hip/hip_runtime.h>
#include <hip/hip_bf16.h>

// GCN 2-layer via CSR gather:
//   dis = rsqrt(indeg_by_dst + 1)
//   hs  = bf16( (x@W) * dis[row] )     (GEMM epilogue, fp32 math)
//   out[i] = act( dis[i] * (hs[i] + sum_{s in N(i)} hs[s]) + b )
// CSR via fixed-slab multisplit (bucket = 256 dst nodes). CHUNK=2048 keeps
// the scatter at ~12 waves/CU (R4's CHUNK=16384 ran at 4% occupancy).
// Aggregate: wave-per-2-nodes, packed bf16x2 gathers (32 lanes x 4B per row).

#define FOUT 64
#define BW 256        // nodes per bucket
#define BSH 8
#define MAXB 512      // >= ceil(n/BW)
#define CHUNK 2048    // edges per scatter block (small => TLP)
#define SLAB 6144     // slab capacity (mean 4092 for E=1.6M,B=391; +32 sigma)

__device__ __forceinline__ float bf2f(unsigned int u16) {
    union { unsigned int i; float f; } c;
    c.i = u16 << 16;
    return c.f;
}
__device__ __forceinline__ unsigned short f2bf(float f) {
    union { float f; unsigned int i; } c;
    c.f = f;
    unsigned int i = c.i;
    return (unsigned short)((i + 0x7FFFu + ((i >> 16) & 1u)) >> 16);  // RN-even
}

// ---- init per-bucket cursors to slab bases -------------------------------
__global__ void init_gcur(int* __restrict__ gcur, int B) {
    int b = blockIdx.x * 256 + threadIdx.x;
    if (b < B) gcur[b] = b * SLAB;
}

// ---- multisplit scatter: per-(block,bucket) contiguous runs --------------
__global__ __launch_bounds__(256) void bucket_scatter(
    const int* __restrict__ src, const int* __restrict__ dst,
    int* __restrict__ gcur, int* __restrict__ ebuf, int E, int B) {
    __shared__ int h[MAXB];
    __shared__ int basea[MAXB];
    const int chunk0 = blockIdx.x * CHUNK;
    const int t = threadIdx.x;
    h[t] = 0;
    h[t + 256] = 0;
    __syncthreads();
#pragma unroll
    for (int k = 0; k < CHUNK / 256; k++) {
        int e = chunk0 + k * 256 + t;
        if (e < E) atomicAdd(&h[dst[e] >> BSH], 1);
    }
    __syncthreads();
    for (int b = t; b < B; b += 256) {
        int c = h[b];
        basea[b] = c ? atomicAdd(&gcur[b], c) : 0;
        h[b] = 0;
    }
    __syncthreads();
#pragma unroll
    for (int k = 0; k < CHUNK / 256; k++) {
        int e = chunk0 + k * 256 + t;
        if (e < E) {
            int d = dst[e];
            int b = d >> BSH;
            int r = atomicAdd(&h[b], 1);
            ebuf[basea[b] + r] = src[e] | ((d & (BW - 1)) << 17);  // src < 2^17
        }
    }
}

// ---- scan bucket counts -> bbase (single block) --------------------------
__global__ __launch_bounds__(512) void bucket_scan(const int* __restrict__ gcur,
                                                   int B, int* __restrict__ bbase,
                                                   int* __restrict__ rowptr,
                                                   int n, int E) {
    __shared__ int ts[MAXB];
    int t = threadIdx.x;
    int v = (t < B) ? (gcur[t] - t * SLAB) : 0;
    ts[t] = v;
    __syncthreads();
    for (int off = 1; off < MAXB; off <<= 1) {
        int x = (t >= off) ? ts[t - off] : 0;
        __syncthreads();
        ts[t] += x;
        __syncthreads();
    }
    if (t < B) bbase[t] = ts[t] - v;  // exclusive prefix
    if (t == 0) {
        bbase[B] = E;
        rowptr[n] = E;
    }
}

// ---- per-bucket CSR finalize: degree/scan/rowptr/dis in LDS, direct col --
__global__ __launch_bounds__(512) void csr_build(
    const int* __restrict__ ebuf, const int* __restrict__ gcur,
    const int* __restrict__ bbase, int* __restrict__ rowptr,
    float* __restrict__ dis, int* __restrict__ col, int n) {
    __shared__ int ldeg[BW];
    __shared__ int lscan[BW];
    const int b = blockIdx.x, t = threadIdx.x;
    const int node0 = b << BSH;
    const int nn = min(BW, n - node0);
    const int ebeg = b * SLAB;
    const int cnt = gcur[b] - ebeg;
    const int segbeg = bbase[b];

    if (t < BW) ldeg[t] = 0;
    __syncthreads();
    for (int i = t; i < cnt; i += 512) atomicAdd(&ldeg[ebuf[ebeg + i] >> 17], 1);
    __syncthreads();
    int v = 0;
    if (t < BW) {
        v = ldeg[t];
        lscan[t] = v;
    }
    __syncthreads();
    for (int off = 1; off < BW; off <<= 1) {
        int x = 0;
        if (t < BW && t >= off) x = lscan[t - off];
        __syncthreads();
        if (t < BW) lscan[t] += x;
        __syncthreads();
    }
    if (t < nn) {
        int ex = lscan[t] - v;  // exclusive prefix within bucket
        rowptr[node0 + t] = segbeg + ex;
        dis[node0 + t] = rsqrtf((float)v + 1.0f);  // +1 self-loop
    }
    __syncthreads();
    if (t < BW) ldeg[t] = lscan[t] - v;  // reuse as write cursor
    __syncthreads();
    // direct col writes: confined to this block's ~cnt*4B segment => L2
    // turns them into full-line writebacks (unlike global scatter in R2).
    for (int i = t; i < cnt; i += 512) {
        int w = ebuf[ebeg + i];
        int r = atomicAdd(&ldeg[w >> 17], 1);
        col[segbeg + r] = w & 0x1FFFF;
    }
}

// ---- GEMM: HS[n x 64] = bf16( (X[n x K] @ W[K x 64]) * dis[row] ) --------
template <int K>
__global__ __launch_bounds__(256) void gemm_xw(const float* __restrict__ X,
                                               const float* __restrict__ W,
                                               const float* __restrict__ dis,
                                               unsigned short* __restrict__ HS, int n) {
    constexpr int KP = K + 4;
    __shared__ float xs[64 * KP];
    __shared__ float ws[K * 64];
    const int tid  = threadIdx.x;
    const int row0 = blockIdx.x * 64;

    for (int idx = tid; idx < 64 * K / 4; idx += 256) {
        int r = (idx * 4) / K;
        int c = (idx * 4) % K;
        float4 v = make_float4(0.f, 0.f, 0.f, 0.f);
        if (row0 + r < n) v = *(const float4*)&X[(size_t)(row0 + r) * K + c];
        *(float4*)&xs[r * KP + c] = v;
    }
    for (int idx = tid; idx < K * 64 / 4; idx += 256) {
        *(float4*)&ws[idx * 4] = *(const float4*)&W[idx * 4];
    }
    __syncthreads();

    const int tr = tid >> 4;
    const int tc = tid & 15;
    float acc[4][4];
#pragma unroll
    for (int i = 0; i < 4; i++)
#pragma unroll
        for (int j = 0; j < 4; j++) acc[i][j] = 0.f;

    for (int k = 0; k < K; k += 4) {
        float4 xv[4], wv[4];
#pragma unroll
        for (int i = 0; i < 4; i++) xv[i] = *(float4*)&xs[(tr * 4 + i) * KP + k];
#pragma unroll
        for (int kk = 0; kk < 4; kk++) wv[kk] = *(float4*)&ws[(k + kk) * 64 + tc * 4];
#pragma unroll
        for (int i = 0; i < 4; i++) {
            float xi[4] = {xv[i].x, xv[i].y, xv[i].z, xv[i].w};
#pragma unroll
            for (int kk = 0; kk < 4; kk++) {
                acc[i][0] = fmaf(xi[kk], wv[kk].x, acc[i][0]);
                acc[i][1] = fmaf(xi[kk], wv[kk].y, acc[i][1]);
                acc[i][2] = fmaf(xi[kk], wv[kk].z, acc[i][2]);
                acc[i][3] = fmaf(xi[kk], wv[kk].w, acc[i][3]);
            }
        }
    }
#pragma unroll
    for (int i = 0; i < 4; i++) {
        int r = row0 + tr * 4 + i;
        if (r < n) {
            float dr = dis[r];
            ushort4 o;
            o.x = f2bf(acc[i][0] * dr);
            o.y = f2bf(acc[i][1] * dr);
            o.z = f2bf(acc[i][2] * dr);
            o.w = f2bf(acc[i][3] * dr);
            *(ushort4*)&HS[(size_t)r * FOUT + tc * 4] = o;
        }
    }
}

// ---- aggregate: 2 nodes per wave, packed bf16x2 gathers ------------------
// lanes 0..31 -> node i0 (uint jj = feature pair), lanes 32..63 -> node i1.
template <bool RELU>
__global__ __launch_bounds__(256) void aggregate(
    const unsigned int* __restrict__ hs32, const int* __restrict__ rowptr,
    const int* __restrict__ col, const float* __restrict__ dis,
    const float* __restrict__ bias, float* __restrict__ out, int n) {
    const int wave = blockIdx.x * 4 + (threadIdx.x >> 6);
    const int lane = threadIdx.x & 63;
    const int half = lane >> 5;
    const int jj   = lane & 31;      // uint index within row (features 2jj,2jj+1)
    const int i = wave * 2 + half;
    if (i >= n) return;

    const int beg = rowptr[i], end = rowptr[i + 1];
    unsigned int su = hs32[(size_t)i * 32 + jj];  // self-loop term
    float a0 = bf2f(su & 0xFFFFu);
    float a1 = bf2f(su >> 16);

    const int hb = half << 5;
    for (int chunk = beg; chunk < end; chunk += 32) {
        int m = end - chunk;
        if (m > 32) m = 32;
        int c = (jj < m) ? col[chunk + jj] : 0;  // 32 cols per half-wave
        int q = 0;
        for (; q + 4 <= m; q += 4) {
            int s0 = __shfl(c, hb + q);
            int s1 = __shfl(c, hb + q + 1);
            int s2 = __shfl(c, hb + q + 2);
            int s3 = __shfl(c, hb + q + 3);
            unsigned int u0 = hs32[(size_t)s0 * 32 + jj];
            unsigned int u1 = hs32[(size_t)s1 * 32 + jj];
            unsigned int u2 = hs32[(size_t)s2 * 32 + jj];
            unsigned int u3 = hs32[(size_t)s3 * 32 + jj];
            a0 += bf2f(u0 & 0xFFFFu) + bf2f(u1 & 0xFFFFu) +
                  bf2f(u2 & 0xFFFFu) + bf2f(u3 & 0xFFFFu);
            a1 += bf2f(u0 >> 16) + bf2f(u1 >> 16) +
                  bf2f(u2 >> 16) + bf2f(u3 >> 16);
        }
        for (; q < m; q++) {
            int s = __shfl(c, hb + q);
            unsigned int u = hs32[(size_t)s * 32 + jj];
            a0 += bf2f(u & 0xFFFFu);
            a1 += bf2f(u >> 16);
        }
    }
    float d = dis[i];
    float2 bb = ((const float2*)bias)[jj];
    float v0 = d * a0 + bb.x;
    float v1 = d * a1 + bb.y;
    if (RELU) {
        v0 = fmaxf(v0, 0.0f);
        v1 = fmaxf(v1, 0.0f);
    }
    ((float2*)out)[(size_t)i * 32 + jj] = make_float2(v0, v1);
}

extern "C" void kernel_launch(void* const* d_in, const int* in_sizes, int n_in,
                              void* d_out, int out_size, void* d_ws, size_t ws_size,
                              hipStream_t stream) {
    const float* x  = (const float*)d_in[0];
    const int*   ei = (const int*)d_in[1];
    const float* W1 = (const float*)d_in[2];
    const float* b1 = (const float*)d_in[3];
    const float* W2 = (const float*)d_in[4];
    const float* b2 = (const float*)d_in[5];

    const int n = in_sizes[0] / 128;
    const int E = in_sizes[1] / 2;
    const int* srcp = ei;
    const int* dstp = ei + E;

    float* out = (float*)d_out;

    const int B = (n + BW - 1) / BW;

    // workspace layout
    int*            gcur   = (int*)d_ws;           // MAXB
    int*            bbase  = gcur + MAXB;          // MAXB+4
    int*            rowptr = bbase + MAXB + 4;     // n+4
    int*            col    = rowptr + n + 4;       // E
    float*          dis    = (float*)(col + E);    // n floats
    unsigned short* hs     = (unsigned short*)(dis + n);  // n*64 bf16
    int*            ebuf   = (int*)hs;             // B*SLAB ints — aliases hs
                                                   // (ebuf dead before gemm1 writes hs)

    // CSR build: slab multisplit -> per-bucket LDS finalize
    init_gcur<<<(B + 255) / 256, 256, 0, stream>>>(gcur, B);
    bucket_scatter<<<(E + CHUNK - 1) / CHUNK, 256, 0, stream>>>(srcp, dstp, gcur, ebuf, E, B);
    bucket_scan<<<1, MAXB, 0, stream>>>(gcur, B, bbase, rowptr, n, E);
    csr_build<<<B, 512, 0, stream>>>(ebuf, gcur, bbase, rowptr, dis, col, n);

    // layer 1: hs = bf16((x@W1)*dis) ; out = relu(dis*(hs_self + sum hs[nbr]) + b1)
    gemm_xw<128><<<(n + 63) / 64, 256, 0, stream>>>(x, W1, dis, hs, n);
    aggregate<true><<<(n + 7) / 8, 256, 0, stream>>>(
        (const unsigned int*)hs, rowptr, col, dis, b1, out, n);

    // layer 2: hs = bf16((out@W2)*dis) ; out = dis*(hs_self + sum hs[nbr]) + b2
    gemm_xw<64><<<(n + 63) / 64, 256, 0, stream>>>(out, W2, dis, hs, n);
    aggregate<false><<<(n + 7) / 8, 256, 0, stream>>>(
        (const unsigned int*)hs, rowptr, col, dis, b2, out, n);
}

// Round 8
// 286.784 us; speedup vs baseline: 5.7443x; 1.1315x over previous
//
#include <hip/hip_runtime.h>
#include <hip/hip_bf16.h>

// GCN 2-layer via CSR gather:
//   dis = rsqrt(indeg_by_dst + 1)
//   hs  = bf16( (x@W) * dis[row] )     (GEMM epilogue, fp32 math)
//   out[i] = act( dis[i] * (hs[i] + sum_{s in N(i)} hs[s]) + b )
// CSR via fixed-slab multisplit (bucket = 256 dst nodes). CHUNK=2048 keeps
// the scatter at high occupancy (R4's CHUNK=16384 ran at 4%).
// GEMM: KT=32 K-tiled LDS (R7's full-K staging hit 236 VGPR / 65KB LDS ->
// <17% occupancy and 51us; small tiles restore TLP).
// Aggregate: wave-per-2-nodes, packed bf16x2 gathers.

#define FOUT 64
#define BW 256        // nodes per bucket
#define BSH 8
#define MAXB 512      // >= ceil(n/BW)
#define CHUNK 2048    // edges per scatter block (small => TLP)
#define SLAB 6144     // slab capacity (mean 4092 for E=1.6M,B=391; +32 sigma)

__device__ __forceinline__ float bf2f(unsigned int u16) {
    union { unsigned int i; float f; } c;
    c.i = u16 << 16;
    return c.f;
}
__device__ __forceinline__ unsigned short f2bf(float f) {
    union { float f; unsigned int i; } c;
    c.f = f;
    unsigned int i = c.i;
    return (unsigned short)((i + 0x7FFFu + ((i >> 16) & 1u)) >> 16);  // RN-even
}

// ---- init per-bucket cursors to slab bases -------------------------------
__global__ void init_gcur(int* __restrict__ gcur, int B) {
    int b = blockIdx.x * 256 + threadIdx.x;
    if (b < B) gcur[b] = b * SLAB;
}

// ---- multisplit scatter: per-(block,bucket) contiguous runs --------------
__global__ __launch_bounds__(256) void bucket_scatter(
    const int* __restrict__ src, const int* __restrict__ dst,
    int* __restrict__ gcur, int* __restrict__ ebuf, int E, int B) {
    __shared__ int h[MAXB];
    __shared__ int basea[MAXB];
    const int chunk0 = blockIdx.x * CHUNK;
    const int t = threadIdx.x;
    h[t] = 0;
    h[t + 256] = 0;
    __syncthreads();
#pragma unroll
    for (int k = 0; k < CHUNK / 256; k++) {
        int e = chunk0 + k * 256 + t;
        if (e < E) atomicAdd(&h[dst[e] >> BSH], 1);
    }
    __syncthreads();
    for (int b = t; b < B; b += 256) {
        int c = h[b];
        basea[b] = c ? atomicAdd(&gcur[b], c) : 0;
        h[b] = 0;
    }
    __syncthreads();
#pragma unroll
    for (int k = 0; k < CHUNK / 256; k++) {
        int e = chunk0 + k * 256 + t;
        if (e < E) {
            int d = dst[e];
            int b = d >> BSH;
            int r = atomicAdd(&h[b], 1);
            ebuf[basea[b] + r] = src[e] | ((d & (BW - 1)) << 17);  // src < 2^17
        }
    }
}

// ---- scan bucket counts -> bbase (single block) --------------------------
__global__ __launch_bounds__(512) void bucket_scan(const int* __restrict__ gcur,
                                                   int B, int* __restrict__ bbase,
                                                   int* __restrict__ rowptr,
                                                   int n, int E) {
    __shared__ int ts[MAXB];
    int t = threadIdx.x;
    int v = (t < B) ? (gcur[t] - t * SLAB) : 0;
    ts[t] = v;
    __syncthreads();
    for (int off = 1; off < MAXB; off <<= 1) {
        int x = (t >= off) ? ts[t - off] : 0;
        __syncthreads();
        ts[t] += x;
        __syncthreads();
    }
    if (t < B) bbase[t] = ts[t] - v;  // exclusive prefix
    if (t == 0) {
        bbase[B] = E;
        rowptr[n] = E;
    }
}

// ---- per-bucket CSR finalize: degree/scan/rowptr/dis in LDS, direct col --
__global__ __launch_bounds__(512) void csr_build(
    const int* __restrict__ ebuf, const int* __restrict__ gcur,
    const int* __restrict__ bbase, int* __restrict__ rowptr,
    float* __restrict__ dis, int* __restrict__ col, int n) {
    __shared__ int ldeg[BW];
    __shared__ int lscan[BW];
    const int b = blockIdx.x, t = threadIdx.x;
    const int node0 = b << BSH;
    const int nn = min(BW, n - node0);
    const int ebeg = b * SLAB;
    const int cnt = gcur[b] - ebeg;
    const int segbeg = bbase[b];

    if (t < BW) ldeg[t] = 0;
    __syncthreads();
    for (int i = t; i < cnt; i += 512) atomicAdd(&ldeg[ebuf[ebeg + i] >> 17], 1);
    __syncthreads();
    int v = 0;
    if (t < BW) {
        v = ldeg[t];
        lscan[t] = v;
    }
    __syncthreads();
    for (int off = 1; off < BW; off <<= 1) {
        int x = 0;
        if (t < BW && t >= off) x = lscan[t - off];
        __syncthreads();
        if (t < BW) lscan[t] += x;
        __syncthreads();
    }
    if (t < nn) {
        int ex = lscan[t] - v;  // exclusive prefix within bucket
        rowptr[node0 + t] = segbeg + ex;
        dis[node0 + t] = rsqrtf((float)v + 1.0f);  // +1 self-loop
    }
    __syncthreads();
    if (t < BW) ldeg[t] = lscan[t] - v;  // reuse as write cursor
    __syncthreads();
    // direct col writes: confined to this block's ~cnt*4B segment => L2
    // turns them into full-line writebacks.
    for (int i = t; i < cnt; i += 512) {
        int w = ebuf[ebeg + i];
        int r = atomicAdd(&ldeg[w >> 17], 1);
        col[segbeg + r] = w & 0x1FFFF;
    }
}

// ---- GEMM: HS[n x 64] = bf16( (X[n x K] @ W[K x 64]) * dis[row] ) --------
// KT=32 K-tiles; 64-row blocks; 256 threads, 4x4 microtile.
template <int K>
__global__ __launch_bounds__(256) void gemm_xw(const float* __restrict__ X,
                                               const float* __restrict__ W,
                                               const float* __restrict__ dis,
                                               unsigned short* __restrict__ HS, int n) {
    constexpr int KT = 32;
    constexpr int KP = KT + 4;
    __shared__ float xs[64 * KP];   // 9216 B
    __shared__ float ws[KT * 64];   // 8192 B
    const int tid  = threadIdx.x;
    const int row0 = blockIdx.x * 64;

    const int tr = tid >> 4;
    const int tc = tid & 15;
    float acc[4][4];
#pragma unroll
    for (int i = 0; i < 4; i++)
#pragma unroll
        for (int j = 0; j < 4; j++) acc[i][j] = 0.f;

    // X stage mapping: 64 rows x 8 float4 (32 floats = one 128B line per row)
    const int sxr = tid >> 3;            // 0..31 (+32 on second pass)
    const int sxc = (tid & 7) << 2;      // 0,4,...,28
    // W stage mapping: KT rows x 16 float4
    const int swk = tid >> 4;            // 0..15 (+16 on second pass)
    const int swc = (tid & 15) << 2;

#pragma unroll 1
    for (int k0 = 0; k0 < K; k0 += KT) {
#pragma unroll
        for (int l = 0; l < 2; l++) {
            int r = sxr + l * 32;
            float4 v = make_float4(0.f, 0.f, 0.f, 0.f);
            if (row0 + r < n) v = *(const float4*)&X[(size_t)(row0 + r) * K + k0 + sxc];
            *(float4*)&xs[r * KP + sxc] = v;
        }
#pragma unroll
        for (int l = 0; l < 2; l++) {
            int kk = swk + l * 16;
            *(float4*)&ws[kk * 64 + swc] = *(const float4*)&W[(size_t)(k0 + kk) * 64 + swc];
        }
        __syncthreads();
#pragma unroll
        for (int k = 0; k < KT; k += 4) {
            float4 xv[4], wv[4];
#pragma unroll
            for (int i = 0; i < 4; i++) xv[i] = *(float4*)&xs[(tr * 4 + i) * KP + k];
#pragma unroll
            for (int kk = 0; kk < 4; kk++) wv[kk] = *(float4*)&ws[(k + kk) * 64 + tc * 4];
#pragma unroll
            for (int i = 0; i < 4; i++) {
                float xi[4] = {xv[i].x, xv[i].y, xv[i].z, xv[i].w};
#pragma unroll
                for (int kk = 0; kk < 4; kk++) {
                    acc[i][0] = fmaf(xi[kk], wv[kk].x, acc[i][0]);
                    acc[i][1] = fmaf(xi[kk], wv[kk].y, acc[i][1]);
                    acc[i][2] = fmaf(xi[kk], wv[kk].z, acc[i][2]);
                    acc[i][3] = fmaf(xi[kk], wv[kk].w, acc[i][3]);
                }
            }
        }
        __syncthreads();
    }

#pragma unroll
    for (int i = 0; i < 4; i++) {
        int r = row0 + tr * 4 + i;
        if (r < n) {
            float dr = dis[r];
            ushort4 o;
            o.x = f2bf(acc[i][0] * dr);
            o.y = f2bf(acc[i][1] * dr);
            o.z = f2bf(acc[i][2] * dr);
            o.w = f2bf(acc[i][3] * dr);
            *(ushort4*)&HS[(size_t)r * FOUT + tc * 4] = o;
        }
    }
}

// ---- aggregate: 2 nodes per wave, packed bf16x2 gathers ------------------
template <bool RELU>
__global__ __launch_bounds__(256) void aggregate(
    const unsigned int* __restrict__ hs32, const int* __restrict__ rowptr,
    const int* __restrict__ col, const float* __restrict__ dis,
    const float* __restrict__ bias, float* __restrict__ out, int n) {
    const int wave = blockIdx.x * 4 + (threadIdx.x >> 6);
    const int lane = threadIdx.x & 63;
    const int half = lane >> 5;
    const int jj   = lane & 31;      // uint index within row (features 2jj,2jj+1)
    const int i = wave * 2 + half;
    if (i >= n) return;

    const int beg = rowptr[i], end = rowptr[i + 1];
    unsigned int su = hs32[(size_t)i * 32 + jj];  // self-loop term
    float a0 = bf2f(su & 0xFFFFu);
    float a1 = bf2f(su >> 16);

    const int hb = half << 5;
    for (int chunk = beg; chunk < end; chunk += 32) {
        int m = end - chunk;
        if (m > 32) m = 32;
        int c = (jj < m) ? col[chunk + jj] : 0;  // 32 cols per half-wave
        int q = 0;
        for (; q + 4 <= m; q += 4) {
            int s0 = __shfl(c, hb + q);
            int s1 = __shfl(c, hb + q + 1);
            int s2 = __shfl(c, hb + q + 2);
            int s3 = __shfl(c, hb + q + 3);
            unsigned int u0 = hs32[(size_t)s0 * 32 + jj];
            unsigned int u1 = hs32[(size_t)s1 * 32 + jj];
            unsigned int u2 = hs32[(size_t)s2 * 32 + jj];
            unsigned int u3 = hs32[(size_t)s3 * 32 + jj];
            a0 += bf2f(u0 & 0xFFFFu) + bf2f(u1 & 0xFFFFu) +
                  bf2f(u2 & 0xFFFFu) + bf2f(u3 & 0xFFFFu);
            a1 += bf2f(u0 >> 16) + bf2f(u1 >> 16) +
                  bf2f(u2 >> 16) + bf2f(u3 >> 16);
        }
        for (; q < m; q++) {
            int s = __shfl(c, hb + q);
            unsigned int u = hs32[(size_t)s * 32 + jj];
            a0 += bf2f(u & 0xFFFFu);
            a1 += bf2f(u >> 16);
        }
    }
    float d = dis[i];
    float2 bb = ((const float2*)bias)[jj];
    float v0 = d * a0 + bb.x;
    float v1 = d * a1 + bb.y;
    if (RELU) {
        v0 = fmaxf(v0, 0.0f);
        v1 = fmaxf(v1, 0.0f);
    }
    ((float2*)out)[(size_t)i * 32 + jj] = make_float2(v0, v1);
}

extern "C" void kernel_launch(void* const* d_in, const int* in_sizes, int n_in,
                              void* d_out, int out_size, void* d_ws, size_t ws_size,
                              hipStream_t stream) {
    const float* x  = (const float*)d_in[0];
    const int*   ei = (const int*)d_in[1];
    const float* W1 = (const float*)d_in[2];
    const float* b1 = (const float*)d_in[3];
    const float* W2 = (const float*)d_in[4];
    const float* b2 = (const float*)d_in[5];

    const int n = in_sizes[0] / 128;
    const int E = in_sizes[1] / 2;
    const int* srcp = ei;
    const int* dstp = ei + E;

    float* out = (float*)d_out;

    const int B = (n + BW - 1) / BW;

    // workspace layout
    int*            gcur   = (int*)d_ws;           // MAXB
    int*            bbase  = gcur + MAXB;          // MAXB+4
    int*            rowptr = bbase + MAXB + 4;     // n+4
    int*            col    = rowptr + n + 4;       // E
    float*          dis    = (float*)(col + E);    // n floats
    unsigned short* hs     = (unsigned short*)(dis + n);  // n*64 bf16
    int*            ebuf   = (int*)hs;             // B*SLAB ints — aliases hs
                                                   // (ebuf dead before gemm1 writes hs)

    // CSR build: slab multisplit -> per-bucket LDS finalize
    init_gcur<<<(B + 255) / 256, 256, 0, stream>>>(gcur, B);
    bucket_scatter<<<(E + CHUNK - 1) / CHUNK, 256, 0, stream>>>(srcp, dstp, gcur, ebuf, E, B);
    bucket_scan<<<1, MAXB, 0, stream>>>(gcur, B, bbase, rowptr, n, E);
    csr_build<<<B, 512, 0, stream>>>(ebuf, gcur, bbase, rowptr, dis, col, n);

    // layer 1: hs = bf16((x@W1)*dis) ; out = relu(dis*(hs_self + sum hs[nbr]) + b1)
    gemm_xw<128><<<(n + 63) / 64, 256, 0, stream>>>(x, W1, dis, hs, n);
    aggregate<true><<<(n + 7) / 8, 256, 0, stream>>>(
        (const unsigned int*)hs, rowptr, col, dis, b1, out, n);

    // layer 2: hs = bf16((out@W2)*dis) ; out = dis*(hs_self + sum hs[nbr]) + b2
    gemm_xw<64><<<(n + 63) / 64, 256, 0, stream>>>(out, W2, dis, hs, n);
    aggregate<false><<<(n + 7) / 8, 256, 0, stream>>>(
        (const unsigned int*)hs, rowptr, col, dis, b2, out, n);
}

// Round 9
// 241.867 us; speedup vs baseline: 6.8110x; 1.1857x over previous
//
#include <hip/hip_runtime.h>
#include <hip/hip_bf16.h>

// GCN 2-layer via CSR gather:
//   dis = rsqrt(indeg_by_dst + 1)
//   hs  = bf16( (x@W) * dis[row] )     (GEMM epilogue, fp32 math)
//   out[i] = act( dis[i] * (hs[i] + sum_{s in N(i)} hs[s]) + b )
// CSR build is a fully DETERMINISTIC two-pass multisplit (radix-sort style):
// per-block histogram matrix -> per-bucket scan -> placement at precomputed
// bases. Zero global atomics (R7's 306K reservation atomics on 391 hot
// addresses were cross-XCD line ping-pong). csr_build ranks IN PLACE in ebuf
// (register-staged) and emits packed rowinfo=(beg<<8|deg) in slab layout --
// no compaction, no col array, no bucket_scan.

#define FOUT 64
#define BW 256        // nodes per bucket
#define BSH 8
#define MAXB 512      // >= ceil(n/BW), power of 2
#define CHUNK 4096    // edges per hist/place block; nblk = ceil(E/CHUNK) <= 512
#define SLAB 6144     // slab capacity per bucket (mean 4092 for E=1.6M,B=391)

__device__ __forceinline__ float bf2f(unsigned int u16) {
    union { unsigned int i; float f; } c;
    c.i = u16 << 16;
    return c.f;
}
__device__ __forceinline__ unsigned short f2bf(float f) {
    union { float f; unsigned int i; } c;
    c.f = f;
    unsigned int i = c.i;
    return (unsigned short)((i + 0x7FFFu + ((i >> 16) & 1u)) >> 16);  // RN-even
}

// ---- pass A: per-block bucket histogram -> cnt[blk][bucket] --------------
__global__ __launch_bounds__(512) void edge_hist(const int* __restrict__ dst,
                                                 int* __restrict__ cnt, int E) {
    __shared__ int h[MAXB];
    const int blk = blockIdx.x, t = threadIdx.x;
    h[t] = 0;
    __syncthreads();
    const int e0 = blk * CHUNK;
#pragma unroll
    for (int k = 0; k < CHUNK / 512; k++) {
        int e = e0 + k * 512 + t;
        if (e < E) atomicAdd(&h[dst[e] >> BSH], 1);
    }
    __syncthreads();
    cnt[blk * MAXB + t] = h[t];
}

// ---- pass B: per-bucket exclusive scan over blocks -> absolute bases -----
__global__ __launch_bounds__(512) void col_scan(int* __restrict__ cnt, int nblk,
                                                int* __restrict__ gcnt) {
    __shared__ int ts[512];
    const int b = blockIdx.x;  // bucket
    const int t = threadIdx.x;
    int v = (t < nblk) ? cnt[t * MAXB + b] : 0;
    ts[t] = v;
    __syncthreads();
    for (int off = 1; off < 512; off <<= 1) {
        int x = (t >= off) ? ts[t - off] : 0;
        __syncthreads();
        ts[t] += x;
        __syncthreads();
    }
    if (t < nblk) cnt[t * MAXB + b] = b * SLAB + ts[t] - v;  // abs base
    if (t == 511) gcnt[b] = ts[511];                          // bucket total
}

// ---- pass C: placement at precomputed bases (no global atomics) ----------
__global__ __launch_bounds__(512) void edge_place(
    const int* __restrict__ src, const int* __restrict__ dst,
    const int* __restrict__ cnt, int* __restrict__ ebuf, int E) {
    __shared__ int lbase[MAXB];
    __shared__ int cur[MAXB];
    const int blk = blockIdx.x, t = threadIdx.x;
    lbase[t] = cnt[blk * MAXB + t];
    cur[t] = 0;
    __syncthreads();
    const int e0 = blk * CHUNK;
#pragma unroll
    for (int k = 0; k < CHUNK / 512; k++) {
        int e = e0 + k * 512 + t;
        if (e < E) {
            int d = dst[e];
            int b = d >> BSH;
            int r = atomicAdd(&cur[b], 1);  // LDS only
            ebuf[lbase[b] + r] = src[e] | ((d & (BW - 1)) << 17);  // src < 2^17
        }
    }
}

// ---- per-bucket finalize: degree/scan/dis/rowinfo, rank ebuf IN PLACE ----
__global__ __launch_bounds__(512) void csr_build(
    int* __restrict__ ebuf, const int* __restrict__ gcnt,
    unsigned int* __restrict__ rowinfo, float* __restrict__ dis, int n) {
    __shared__ int ldeg[BW];
    __shared__ int lscan[BW];
    const int b = blockIdx.x, t = threadIdx.x;
    const int node0 = b << BSH;
    const int nn = min(BW, n - node0);
    const int ebeg = b * SLAB;
    const int cnt = gcnt[b];

    // stage this bucket's edge words in registers (SLAB/512 = 12 max)
    int w[SLAB / 512];
#pragma unroll
    for (int k = 0; k < SLAB / 512; k++) {
        int idx = t + k * 512;
        w[k] = (idx < cnt) ? ebuf[ebeg + idx] : -1;
    }
    if (t < BW) ldeg[t] = 0;
    __syncthreads();
#pragma unroll
    for (int k = 0; k < SLAB / 512; k++)
        if (w[k] >= 0) atomicAdd(&ldeg[w[k] >> 17], 1);
    __syncthreads();
    int v = 0;
    if (t < BW) {
        v = ldeg[t];
        lscan[t] = v;
    }
    __syncthreads();
    for (int off = 1; off < BW; off <<= 1) {
        int x = 0;
        if (t < BW && t >= off) x = lscan[t - off];
        __syncthreads();
        if (t < BW) lscan[t] += x;
        __syncthreads();
    }
    if (t < nn) {
        int ex = lscan[t] - v;  // exclusive prefix within bucket
        rowinfo[node0 + t] = ((unsigned int)(ebeg + ex) << 8) | (unsigned int)v;
        dis[node0 + t] = rsqrtf((float)v + 1.0f);  // +1 self-loop
    }
    __syncthreads();
    if (t < BW) ldeg[t] = lscan[t] - v;  // reuse as write cursor
    __syncthreads();
    // all words are register-staged (barrier above) => in-place rewrite safe
#pragma unroll
    for (int k = 0; k < SLAB / 512; k++)
        if (w[k] >= 0) {
            int r = atomicAdd(&ldeg[w[k] >> 17], 1);
            ebuf[ebeg + r] = w[k] & 0x1FFFF;  // ebuf becomes col
        }
}

// ---- GEMM: HS[n x 64] = bf16( (X[n x K] @ W[K x 64]) * dis[row] ) --------
// KT=32 K-tiles; 64-row blocks; 256 threads, 4x4 microtile.
template <int K>
__global__ __launch_bounds__(256) void gemm_xw(const float* __restrict__ X,
                                               const float* __restrict__ W,
                                               const float* __restrict__ dis,
                                               unsigned short* __restrict__ HS, int n) {
    constexpr int KT = 32;
    constexpr int KP = KT + 4;
    __shared__ float xs[64 * KP];   // 9216 B
    __shared__ float ws[KT * 64];   // 8192 B
    const int tid  = threadIdx.x;
    const int row0 = blockIdx.x * 64;

    const int tr = tid >> 4;
    const int tc = tid & 15;
    float acc[4][4];
#pragma unroll
    for (int i = 0; i < 4; i++)
#pragma unroll
        for (int j = 0; j < 4; j++) acc[i][j] = 0.f;

    const int sxr = tid >> 3;            // 0..31 (+32 on second pass)
    const int sxc = (tid & 7) << 2;      // 0,4,...,28
    const int swk = tid >> 4;            // 0..15 (+16 on second pass)
    const int swc = (tid & 15) << 2;

#pragma unroll 1
    for (int k0 = 0; k0 < K; k0 += KT) {
#pragma unroll
        for (int l = 0; l < 2; l++) {
            int r = sxr + l * 32;
            float4 v = make_float4(0.f, 0.f, 0.f, 0.f);
            if (row0 + r < n) v = *(const float4*)&X[(size_t)(row0 + r) * K + k0 + sxc];
            *(float4*)&xs[r * KP + sxc] = v;
        }
#pragma unroll
        for (int l = 0; l < 2; l++) {
            int kk = swk + l * 16;
            *(float4*)&ws[kk * 64 + swc] = *(const float4*)&W[(size_t)(k0 + kk) * 64 + swc];
        }
        __syncthreads();
#pragma unroll
        for (int k = 0; k < KT; k += 4) {
            float4 xv[4], wv[4];
#pragma unroll
            for (int i = 0; i < 4; i++) xv[i] = *(float4*)&xs[(tr * 4 + i) * KP + k];
#pragma unroll
            for (int kk = 0; kk < 4; kk++) wv[kk] = *(float4*)&ws[(k + kk) * 64 + tc * 4];
#pragma unroll
            for (int i = 0; i < 4; i++) {
                float xi[4] = {xv[i].x, xv[i].y, xv[i].z, xv[i].w};
#pragma unroll
                for (int kk = 0; kk < 4; kk++) {
                    acc[i][0] = fmaf(xi[kk], wv[kk].x, acc[i][0]);
                    acc[i][1] = fmaf(xi[kk], wv[kk].y, acc[i][1]);
                    acc[i][2] = fmaf(xi[kk], wv[kk].z, acc[i][2]);
                    acc[i][3] = fmaf(xi[kk], wv[kk].w, acc[i][3]);
                }
            }
        }
        __syncthreads();
    }

#pragma unroll
    for (int i = 0; i < 4; i++) {
        int r = row0 + tr * 4 + i;
        if (r < n) {
            float dr = dis[r];
            ushort4 o;
            o.x = f2bf(acc[i][0] * dr);
            o.y = f2bf(acc[i][1] * dr);
            o.z = f2bf(acc[i][2] * dr);
            o.w = f2bf(acc[i][3] * dr);
            *(ushort4*)&HS[(size_t)r * FOUT + tc * 4] = o;
        }
    }
}

// ---- aggregate: 2 nodes per wave, packed bf16x2 gathers ------------------
template <bool RELU>
__global__ __launch_bounds__(256) void aggregate(
    const unsigned int* __restrict__ hs32, const unsigned int* __restrict__ rowinfo,
    const int* __restrict__ col, const float* __restrict__ dis,
    const float* __restrict__ bias, float* __restrict__ out, int n) {
    const int wave = blockIdx.x * 4 + (threadIdx.x >> 6);
    const int lane = threadIdx.x & 63;
    const int half = lane >> 5;
    const int jj   = lane & 31;      // uint index within row (features 2jj,2jj+1)
    const int i = wave * 2 + half;
    if (i >= n) return;

    const unsigned int info = rowinfo[i];
    const int beg = (int)(info >> 8);
    const int end = beg + (int)(info & 255u);
    unsigned int su = hs32[(size_t)i * 32 + jj];  // self-loop term
    float a0 = bf2f(su & 0xFFFFu);
    float a1 = bf2f(su >> 16);

    const int hb = half << 5;
    for (int chunk = beg; chunk < end; chunk += 32) {
        int m = end - chunk;
        if (m > 32) m = 32;
        int c = (jj < m) ? col[chunk + jj] : 0;  // 32 cols per half-wave
        int q = 0;
        for (; q + 4 <= m; q += 4) {
            int s0 = __shfl(c, hb + q);
            int s1 = __shfl(c, hb + q + 1);
            int s2 = __shfl(c, hb + q + 2);
            int s3 = __shfl(c, hb + q + 3);
            unsigned int u0 = hs32[(size_t)s0 * 32 + jj];
            unsigned int u1 = hs32[(size_t)s1 * 32 + jj];
            unsigned int u2 = hs32[(size_t)s2 * 32 + jj];
            unsigned int u3 = hs32[(size_t)s3 * 32 + jj];
            a0 += bf2f(u0 & 0xFFFFu) + bf2f(u1 & 0xFFFFu) +
                  bf2f(u2 & 0xFFFFu) + bf2f(u3 & 0xFFFFu);
            a1 += bf2f(u0 >> 16) + bf2f(u1 >> 16) +
                  bf2f(u2 >> 16) + bf2f(u3 >> 16);
        }
        for (; q < m; q++) {
            int s = __shfl(c, hb + q);
            unsigned int u = hs32[(size_t)s * 32 + jj];
            a0 += bf2f(u & 0xFFFFu);
            a1 += bf2f(u >> 16);
        }
    }
    float d = dis[i];
    float2 bb = ((const float2*)bias)[jj];
    float v0 = d * a0 + bb.x;
    float v1 = d * a1 + bb.y;
    if (RELU) {
        v0 = fmaxf(v0, 0.0f);
        v1 = fmaxf(v1, 0.0f);
    }
    ((float2*)out)[(size_t)i * 32 + jj] = make_float2(v0, v1);
}

extern "C" void kernel_launch(void* const* d_in, const int* in_sizes, int n_in,
                              void* d_out, int out_size, void* d_ws, size_t ws_size,
                              hipStream_t stream) {
    const float* x  = (const float*)d_in[0];
    const int*   ei = (const int*)d_in[1];
    const float* W1 = (const float*)d_in[2];
    const float* b1 = (const float*)d_in[3];
    const float* W2 = (const float*)d_in[4];
    const float* b2 = (const float*)d_in[5];

    const int n = in_sizes[0] / 128;
    const int E = in_sizes[1] / 2;
    const int* srcp = ei;
    const int* dstp = ei + E;

    float* out = (float*)d_out;

    const int B = (n + BW - 1) / BW;
    const int nblk = (E + CHUNK - 1) / CHUNK;  // <= 512 required

    // workspace layout
    int*            cnt     = (int*)d_ws;                     // 512*MAXB
    int*            gcnt    = cnt + 512 * MAXB;               // MAXB
    unsigned int*   rowinfo = (unsigned int*)(gcnt + MAXB);   // n
    float*          dis     = (float*)(rowinfo + n);          // n
    int*            ebuf    = (int*)(dis + n);                // B*SLAB (becomes col)
    unsigned short* hs      = (unsigned short*)(ebuf + (size_t)B * SLAB);  // n*64 bf16

    // deterministic multisplit CSR build (no global atomics anywhere)
    edge_hist<<<nblk, 512, 0, stream>>>(dstp, cnt, E);
    col_scan<<<B, 512, 0, stream>>>(cnt, nblk, gcnt);
    edge_place<<<nblk, 512, 0, stream>>>(srcp, dstp, cnt, ebuf, E);
    csr_build<<<B, 512, 0, stream>>>(ebuf, gcnt, rowinfo, dis, n);

    // layer 1: hs = bf16((x@W1)*dis) ; out = relu(dis*(hs_self + sum hs[nbr]) + b1)
    gemm_xw<128><<<(n + 63) / 64, 256, 0, stream>>>(x, W1, dis, hs, n);
    aggregate<true><<<(n + 7) / 8, 256, 0, stream>>>(
        (const unsigned int*)hs, rowinfo, ebuf, dis, b1, out, n);

    // layer 2: hs = bf16((out@W2)*dis) ; out = dis*(hs_self + sum hs[nbr]) + b2
    gemm_xw<64><<<(n + 63) / 64, 256, 0, stream>>>(out, W2, dis, hs, n);
    aggregate<false><<<(n + 7) / 8, 256, 0, stream>>>(
        (const unsigned int*)hs, rowinfo, ebuf, dis, b2, out, n);
}